// Round 12
// baseline (2944.545 us; speedup 1.0000x reference)
//
#include <hip/hip_runtime.h>

typedef __attribute__((ext_vector_type(8))) short short8;
typedef __attribute__((ext_vector_type(4))) float f32x4;

#define SEQ_BLOCKS 64

__device__ __forceinline__ unsigned short f2bf(float f) {
  unsigned u = __float_as_uint(f);
  u = u + 0x7fffu + ((u >> 16) & 1u);
  return (unsigned short)(u >> 16);
}
__device__ __forceinline__ float h2f(unsigned short u) {
  _Float16 h;
  __builtin_memcpy(&h, &u, 2);
  return (float)h;
}
__device__ __forceinline__ void gload16(const void* g, void* l) {
  __builtin_amdgcn_global_load_lds(
      (const __attribute__((address_space(1))) unsigned int*)g,
      (__attribute__((address_space(3))) unsigned int*)l, 16, 0, 0);
}
__device__ __forceinline__ float fast_sigmoid(float x) {
  return 1.0f / (1.0f + __expf(-x));
}
__device__ __forceinline__ float fast_tanh(float x) {
  return 2.0f / (1.0f + __expf(-2.0f * x)) - 1.0f;
}

// ---------- elementwise fp32 -> bf16 convert (vectorized) ----------
__global__ void k_conv_bf16(const float* __restrict__ in, unsigned short* __restrict__ out) {
  size_t i = ((size_t)blockIdx.x * 256 + threadIdx.x) * 4;
  float4 v = *(const float4*)(in + i);
  unsigned short o[4] = {f2bf(v.x), f2bf(v.y), f2bf(v.z), f2bf(v.w)};
  *(uint2*)(out + i) = *(const uint2*)o;
}

// ---------- h0 into slot 0: hstep[0][sb][row][16] ----------
__global__ void k_h0t(const float* __restrict__ hidden, unsigned short* __restrict__ hT) {
  int sb = blockIdx.x;
  int row = threadIdx.x >> 2, c4 = (threadIdx.x & 3) * 4;
  float4 v = *(const float4*)(hidden + (size_t)row * 1024 + sb * 16 + c4);
  unsigned short o[4] = {f2bf(v.x), f2bf(v.y), f2bf(v.z), f2bf(v.w)};
  unsigned long long u;
  __builtin_memcpy(&u, o, 8);
  *(unsigned long long*)(hT + (size_t)sb * 1024 + row * 16 + c4) = u;
}

// ---------- transpose + convert: out[c][r] = bf16(in[r][c]) ----------
__global__ void k_transpose(const float* __restrict__ in, unsigned short* __restrict__ out,
                            int R, int C) {
  __shared__ float tile[32][33];
  int bx = blockIdx.x * 32, by = blockIdx.y * 32;
  int tx = threadIdx.x & 31, ty = threadIdx.x >> 5;  // ty 0..7
  for (int i = 0; i < 32; i += 8)
    tile[ty + i][tx] = in[(size_t)(by + ty + i) * C + bx + tx];
  __syncthreads();
  for (int i = 0; i < 32; i += 8)
    out[(size_t)(bx + ty + i) * R + by + tx] = f2bf(tile[tx][ty + i]);
}

// ---------- generic bf16 GEMM, C = A @ B^T, A[M][K], B[N][K] bf16, bf16 out ----------
__global__ __launch_bounds__(256) void k_gemm_bt(
    const unsigned short* __restrict__ A, const unsigned short* __restrict__ B,
    unsigned short* __restrict__ C, int M, int N, int K) {
  __shared__ unsigned short As[128 * 32];
  __shared__ unsigned short Bs[128 * 32];
  const int tid = threadIdx.x;
  const int wv = tid >> 6, l = tid & 63;
  const int m0 = blockIdx.y * 128, n0 = blockIdx.x * 128;
  const int wr = (wv >> 1) * 64, wc = (wv & 1) * 64;
  f32x4 acc[4][4] = {};
  for (int k0 = 0; k0 < K; k0 += 32) {
#pragma unroll
    for (int j = 0; j < 2; ++j) {
      int c = wv * 128 + j * 64 + l;
      int row = c >> 2, kc = (c & 3) * 8;
      gload16(A + (size_t)(m0 + row) * K + k0 + kc, (char*)As + c * 16);
      gload16(B + (size_t)(n0 + row) * K + k0 + kc, (char*)Bs + c * 16);
    }
    __syncthreads();
    short8 af[4], bfr[4];
#pragma unroll
    for (int rf = 0; rf < 4; ++rf)
      af[rf] = *(const short8*)(As + (wr + rf * 16 + (l & 15)) * 32 + (l >> 4) * 8);
#pragma unroll
    for (int cf = 0; cf < 4; ++cf)
      bfr[cf] = *(const short8*)(Bs + (wc + cf * 16 + (l & 15)) * 32 + (l >> 4) * 8);
#pragma unroll
    for (int rf = 0; rf < 4; ++rf)
#pragma unroll
      for (int cf = 0; cf < 4; ++cf)
        acc[rf][cf] = __builtin_amdgcn_mfma_f32_16x16x32_bf16(af[rf], bfr[cf], acc[rf][cf], 0, 0, 0);
    __syncthreads();
  }
#pragma unroll
  for (int cf = 0; cf < 4; ++cf) {
    int col = n0 + wc + cf * 16 + (l & 15);
#pragma unroll
    for (int rf = 0; rf < 4; ++rf) {
#pragma unroll
      for (int i = 0; i < 4; ++i) {
        int row = m0 + wr + rf * 16 + (l >> 4) * 4 + i;
        C[(size_t)row * N + col] = f2bf(acc[rf][cf][i]);
      }
    }
  }
}

// ---------- combined bias ----------
__global__ void k_bias(const float* __restrict__ Wxg, const float* __restrict__ bxg,
                       const float* __restrict__ b_in, const float* __restrict__ Whg,
                       const float* __restrict__ bhg, const float* __restrict__ b_hid,
                       float* __restrict__ gbias) {
  int col = blockIdx.x * 64 + (threadIdx.x >> 2);
  int p = threadIdx.x & 3;
  const float* wx = Wxg + (size_t)col * 1024;
  const float* wh = Whg + (size_t)col * 1024;
  float s = 0.f;
  for (int k = p * 256; k < p * 256 + 256; ++k)
    s += wx[k] * b_in[k] + wh[k] * b_hid[k];
  s += __shfl_down(s, 2, 4);
  s += __shfl_down(s, 1, 4);
  if (p == 0) gbias[col] = s + bxg[col] + bhg[col];
}

// ---------- persistent sequential LSTM scan (x-path GEMM fused in) ----------
// R11 scan + in-scan Wx GEMM: gates(t) = Whc@h(t) + Wxc@x(t) + gbias.
// X-fragments (no cross-block dependency) are loaded BEFORE the h-poll and
// their 128 MFMAs run while h-loads are in flight -> the extra work hides
// inside the inter-block visibility window. GX buffer/GEMM deleted entirely.
// Exchange protocol unchanged (best-measured): depth-256 hstep slots, sc0/sc1
// u64 h-stores, vmcnt+barrier+packed tag, 1-line poll, cached fresh A-loads.
__global__ __launch_bounds__(256, 1) void k_lstm_seq(
    const unsigned short* __restrict__ Xbf,  // bf16 [256][64][1024]
    const unsigned short* __restrict__ Wxc,  // bf16 [4096][1024]
    const unsigned short* __restrict__ Whc,  // bf16 [4096][1024]
    const float* __restrict__ gbias,         // f32 [4096]
    const float* __restrict__ cell,          // [64][1024] f32
    unsigned short* __restrict__ hstep,      // bf16 [257][64][64][16]
    float* __restrict__ out,                 // h [64][1024], c [64][1024] f32
    unsigned* __restrict__ flags) {          // [4 groups][32 u32]: 16 tags/line
  __shared__ float pbuf[34816];              // 139 KB: (t&1)*17408 + s*4352 + gc*68 + b
  const int tid = threadIdx.x;
  const int wv = tid >> 6, l = tid & 63;
  const int bid = blockIdx.x;
  const int a = l & 15, q = l >> 4;

  // ---- weights: gate-col ct*1024 + bid*16 + a; k = wv*256 + u*32 + q*8 ----
  short8 wh[4][8], wx[4][8];
#pragma unroll
  for (int ct = 0; ct < 4; ++ct)
#pragma unroll
    for (int u = 0; u < 8; ++u) {
      size_t off = (size_t)(ct * 1024 + bid * 16 + a) * 1024 + wv * 256 + u * 32 + q * 8;
      wh[ct][u] = *(const short8*)(Whc + off);
      wx[ct][u] = *(const short8*)(Wxc + off);
    }

  // elementwise ownership: batch-row eb, h-cols ej..ej+3
  const int eb = tid >> 2;
  const int ej = (tid & 3) * 4;
  float c_reg[4];
  {
    float4 c4 = *(const float4*)(cell + (size_t)eb * 1024 + bid * 16 + ej);
    c_reg[0] = c4.x; c_reg[1] = c4.y; c_reg[2] = c4.z; c_reg[3] = c4.w;
  }
  float gb[4][4];
#pragma unroll
  for (int g = 0; g < 4; ++g)
#pragma unroll
    for (int i = 0; i < 4; ++i)
      gb[g][i] = gbias[g * 1024 + bid * 16 + ej + i];

  // A-load base inside an hstep slot: src = wv*16 + 2u + (q>>1), row a, col8=(q&1)*8
  const size_t abase = (size_t)(wv * 16 + (q >> 1)) * 1024 + a * 16 + (q & 1) * 8;
  // poll: wave wv's 16 sources' tags all live in line wv
  const unsigned* pollp = flags + wv * 32 + a;

  for (int t = 0; t < 256; ++t) {
    // --- issue X-fragment loads (independent of h; latency hides under poll) ---
    const unsigned short* xb = Xbf + ((size_t)t << 16) + (size_t)a * 1024 + wv * 256 + q * 8;
    short8 afx[4][8];
#pragma unroll
    for (int u = 0; u < 8; ++u)
#pragma unroll
      for (int rt = 0; rt < 4; ++rt)
        afx[rt][u] = *(const short8*)(xb + (size_t)rt * 16384 + u * 32);

    // --- wait for the 16 source-block tags (ONE line per wave) ---
    if (t > 0) {
      const unsigned tgt = (unsigned)t;
      for (;;) {
        unsigned v = __hip_atomic_load(pollp, __ATOMIC_RELAXED, __HIP_MEMORY_SCOPE_AGENT);
        if (__all((int)(v >= tgt))) break;
        __builtin_amdgcn_s_sleep(1);
      }
      __builtin_amdgcn_fence(__ATOMIC_ACQUIRE, "workgroup");
      __builtin_amdgcn_sched_barrier(0);
    }

    // --- issue h-fragment loads (cached; fresh addresses each step) ---
    const unsigned short* hb = hstep + ((size_t)t << 16) + abase;
    short8 afr[4][8];
#pragma unroll
    for (int u = 0; u < 8; ++u)
#pragma unroll
      for (int rt = 0; rt < 4; ++rt)
        afr[rt][u] = *(const short8*)(hb + u * 2048 + rt * 256);

    // --- 128 X-MFMAs (operands ready; runs while h-loads are in flight) ---
    f32x4 acc[4][4] = {};
#pragma unroll
    for (int u = 0; u < 8; ++u)
#pragma unroll
      for (int rt = 0; rt < 4; ++rt)
#pragma unroll
        for (int ct = 0; ct < 4; ++ct)
          acc[rt][ct] = __builtin_amdgcn_mfma_f32_16x16x32_bf16(afx[rt][u], wx[ct][u],
                                                                acc[rt][ct], 0, 0, 0);
    // --- 128 h-MFMAs ---
#pragma unroll
    for (int u = 0; u < 8; ++u)
#pragma unroll
      for (int rt = 0; rt < 4; ++rt)
#pragma unroll
        for (int ct = 0; ct < 4; ++ct)
          acc[rt][ct] = __builtin_amdgcn_mfma_f32_16x16x32_bf16(afr[rt][u], wh[ct][u],
                                                                acc[rt][ct], 0, 0, 0);

    // --- partials to LDS (0-conflict layout): f32x4 over batch ---
    const int pb = (t & 1) * 17408 + wv * 4352;
#pragma unroll
    for (int rt = 0; rt < 4; ++rt)
#pragma unroll
      for (int ct = 0; ct < 4; ++ct) {
        int gc = a * 4 + ct;                              // h-col-major gate-col
        int b0 = (rt * 16 + q * 4) ^ ((((gc) >> 3) & 3) << 2);
        *(f32x4*)&pbuf[pb + gc * 68 + b0] = acc[rt][ct];
      }
    __syncthreads();

    // --- reduce 4 k-slots + gbias, gates for (row eb, cols ej..ej+3) ---
    const int pr = (t & 1) * 17408;
    float sg[4][4];
#pragma unroll
    for (int g = 0; g < 4; ++g) {
#pragma unroll
      for (int i = 0; i < 4; ++i) {
        int gc = (ej + i) * 4 + g;
        int bx = eb ^ ((((gc) >> 3) & 3) << 2);
        float s = pbuf[pr + 0 * 4352 + gc * 68 + bx] + pbuf[pr + 1 * 4352 + gc * 68 + bx] +
                  pbuf[pr + 2 * 4352 + gc * 68 + bx] + pbuf[pr + 3 * 4352 + gc * 68 + bx];
        sg[g][i] = s + gb[g][i];
      }
    }
    float hnew[4];
#pragma unroll
    for (int i = 0; i < 4; ++i) {
      float ig = fast_sigmoid(sg[0][i]);
      float fg = fast_sigmoid(sg[1][i]);
      float gg = fast_tanh(sg[2][i]);
      float og = fast_sigmoid(sg[3][i]);
      c_reg[i] = fg * c_reg[i] + ig * gg;
      hnew[i] = og * fast_tanh(c_reg[i]);
    }

    if (t == 255) {
      float4 h4 = {hnew[0], hnew[1], hnew[2], hnew[3]};
      float4 c4 = {c_reg[0], c_reg[1], c_reg[2], c_reg[3]};
      *(float4*)(out + (size_t)eb * 1024 + bid * 16 + ej) = h4;
      *(float4*)(out + 65536 + (size_t)eb * 1024 + bid * 16 + ej) = c4;
    } else {
      // h(t+1) into FRESH slot t+1 (u64 packed sc0/sc1 stores -> L3)
      unsigned short hs[4] = {f2bf(hnew[0]), f2bf(hnew[1]), f2bf(hnew[2]), f2bf(hnew[3])};
      unsigned long long hv;
      __builtin_memcpy(&hv, hs, 8);
      __hip_atomic_store(
          (unsigned long long*)(hstep + ((size_t)(t + 1) << 16) + (size_t)bid * 1024 +
                                eb * 16 + ej),
          hv, __ATOMIC_RELAXED, __HIP_MEMORY_SCOPE_AGENT);
      asm volatile("s_waitcnt vmcnt(0)" ::: "memory");  // this wave's stores at L3
      __syncthreads();                                   // all 4 waves' stores done
      if (tid == 0)
        __hip_atomic_store(&flags[(bid >> 4) * 32 + (bid & 15)], (unsigned)(t + 1),
                           __ATOMIC_RELAXED, __HIP_MEMORY_SCOPE_AGENT);
    }
  }
}

extern "C" void kernel_launch(void* const* d_in, const int* in_sizes, int n_in,
                              void* d_out, int out_size, void* d_ws, size_t ws_size,
                              hipStream_t stream) {
  const float* x      = (const float*)d_in[0];
  const float* hidden = (const float*)d_in[1];
  const float* cell   = (const float*)d_in[2];
  const float* W_in   = (const float*)d_in[3];
  const float* b_in   = (const float*)d_in[4];
  const float* W_hid  = (const float*)d_in[5];
  const float* b_hid  = (const float*)d_in[6];
  const float* Wx_g   = (const float*)d_in[7];
  const float* bx_g   = (const float*)d_in[8];
  const float* Wh_g   = (const float*)d_in[9];
  const float* bh_g   = (const float*)d_in[10];
  float* out = (float*)d_out;

  char* ws = (char*)d_ws;
  unsigned short* hstep = (unsigned short*)(ws);                 // 33685504 (257 slots)
  unsigned short* Xbf   = (unsigned short*)(ws + 134217728);     // 33554432 (LIVE through scan)
  unsigned short* WxGb  = (unsigned short*)(ws + 167772160);     // 8388608
  unsigned short* WhGb  = (unsigned short*)(ws + 176160768);     // 8388608
  unsigned short* WinT  = (unsigned short*)(ws + 184549376);     // 2097152 (reused for flags)
  unsigned short* WhidT = (unsigned short*)(ws + 186646528);     // 2097152
  unsigned short* Wxc   = (unsigned short*)(ws + 188743680);     // 8388608
  unsigned short* Whc   = (unsigned short*)(ws + 197132288);     // 8388608
  float*          gbias = (float*)(ws + 205520896);              // 16384
  unsigned*       flags = (unsigned*)(ws + 184549376);           // 512 B (overlays WinT)

  // converts
  k_conv_bf16<<<16384, 256, 0, stream>>>(x, Xbf);
  k_conv_bf16<<<4096, 256, 0, stream>>>(Wx_g, WxGb);
  k_conv_bf16<<<4096, 256, 0, stream>>>(Wh_g, WhGb);
  k_transpose<<<dim3(32, 32), 256, 0, stream>>>(W_in, WinT, 1024, 1024);
  k_transpose<<<dim3(32, 32), 256, 0, stream>>>(W_hid, WhidT, 1024, 1024);
  // combined weights: Wxc = WxG @ W_in (via W_in^T), Whc = WhG @ W_hid
  k_gemm_bt<<<dim3(8, 32), 256, 0, stream>>>(WxGb, WinT, Wxc, 4096, 1024, 1024);
  k_gemm_bt<<<dim3(8, 32), 256, 0, stream>>>(WhGb, WhidT, Whc, 4096, 1024, 1024);
  k_bias<<<64, 256, 0, stream>>>(Wx_g, bx_g, b_in, Wh_g, bh_g, b_hid, gbias);
  // h0 into hstep slot 0
  k_h0t<<<64, 256, 0, stream>>>(hidden, hstep);
  // packed tag lines
  hipMemsetAsync(flags, 0, 512, stream);
  // sequential scan (x-path GEMM fused; no GX buffer)
  k_lstm_seq<<<SEQ_BLOCKS, 256, 0, stream>>>(Xbf, Wxc, Whc, gbias, cell, hstep, out, flags);
}

// Round 13
// 2016.517 us; speedup vs baseline: 1.4602x; 1.4602x over previous
//
#include <hip/hip_runtime.h>

typedef __attribute__((ext_vector_type(8))) short short8;
typedef __attribute__((ext_vector_type(4))) float f32x4;

#define SEQ_BLOCKS 64
#define GX_TILES 4096u

__device__ __forceinline__ unsigned short f2bf(float f) {
  unsigned u = __float_as_uint(f);
  u = u + 0x7fffu + ((u >> 16) & 1u);
  return (unsigned short)(u >> 16);
}
__device__ __forceinline__ unsigned short f2h(float f) {
  _Float16 h = (_Float16)f;
  unsigned short r;
  __builtin_memcpy(&r, &h, 2);
  return r;
}
__device__ __forceinline__ float h2f(unsigned short u) {
  _Float16 h;
  __builtin_memcpy(&h, &u, 2);
  return (float)h;
}
__device__ __forceinline__ void gload16(const void* g, void* l) {
  __builtin_amdgcn_global_load_lds(
      (const __attribute__((address_space(1))) unsigned int*)g,
      (__attribute__((address_space(3))) unsigned int*)l, 16, 0, 0);
}
__device__ __forceinline__ float fast_sigmoid(float x) {
  return 1.0f / (1.0f + __expf(-x));
}
__device__ __forceinline__ float fast_tanh(float x) {
  return 2.0f / (1.0f + __expf(-2.0f * x)) - 1.0f;
}
// L2-bypassing (sc0 sc1) atomics for cross-XCD exchange through L3
__device__ __forceinline__ unsigned long long ld_u64(const unsigned long long* p) {
  return __hip_atomic_load(p, __ATOMIC_RELAXED, __HIP_MEMORY_SCOPE_AGENT);
}
__device__ __forceinline__ short8 load_h16(const unsigned short* p) {
  union { unsigned long long u[2]; short8 s; } r;
  r.u[0] = ld_u64((const unsigned long long*)p);
  r.u[1] = ld_u64(((const unsigned long long*)p) + 1);
  return r.s;
}

// ---------- elementwise fp32 -> bf16 convert (vectorized) ----------
__global__ void k_conv_bf16(const float* __restrict__ in, unsigned short* __restrict__ out) {
  size_t i = ((size_t)blockIdx.x * 256 + threadIdx.x) * 4;
  float4 v = *(const float4*)(in + i);
  unsigned short o[4] = {f2bf(v.x), f2bf(v.y), f2bf(v.z), f2bf(v.w)};
  *(uint2*)(out + i) = *(const uint2*)o;
}

// ---------- h0 into transposed hT[0][sb][row][16] ----------
__global__ void k_h0t(const float* __restrict__ hidden, unsigned short* __restrict__ hT) {
  int sb = blockIdx.x;
  int row = threadIdx.x >> 2, c4 = (threadIdx.x & 3) * 4;
  float4 v = *(const float4*)(hidden + (size_t)row * 1024 + sb * 16 + c4);
  unsigned short o[4] = {f2bf(v.x), f2bf(v.y), f2bf(v.z), f2bf(v.w)};
  unsigned long long u;
  __builtin_memcpy(&u, o, 8);
  *(unsigned long long*)(hT + (size_t)sb * 1024 + row * 16 + c4) = u;
}

// ---------- transpose + convert: out[c][r] = bf16(in[r][c]) ----------
__global__ void k_transpose(const float* __restrict__ in, unsigned short* __restrict__ out,
                            int R, int C) {
  __shared__ float tile[32][33];
  int bx = blockIdx.x * 32, by = blockIdx.y * 32;
  int tx = threadIdx.x & 31, ty = threadIdx.x >> 5;  // ty 0..7
  for (int i = 0; i < 32; i += 8)
    tile[ty + i][tx] = in[(size_t)(by + ty + i) * C + bx + tx];
  __syncthreads();
  for (int i = 0; i < 32; i += 8)
    out[(size_t)(bx + ty + i) * R + by + tx] = f2bf(tile[tx][ty + i]);
}

// ---------- generic bf16 GEMM, C = A @ B^T, bf16 out (combine GEMMs) ----------
__global__ __launch_bounds__(256) void k_gemm_bt(
    const unsigned short* __restrict__ A, const unsigned short* __restrict__ B,
    unsigned short* __restrict__ C, int M, int N, int K) {
  __shared__ unsigned short As[128 * 32];
  __shared__ unsigned short Bs[128 * 32];
  const int tid = threadIdx.x;
  const int wv = tid >> 6, l = tid & 63;
  const int m0 = blockIdx.y * 128, n0 = blockIdx.x * 128;
  const int wr = (wv >> 1) * 64, wc = (wv & 1) * 64;
  f32x4 acc[4][4] = {};
  for (int k0 = 0; k0 < K; k0 += 32) {
#pragma unroll
    for (int j = 0; j < 2; ++j) {
      int c = wv * 128 + j * 64 + l;
      int row = c >> 2, kc = (c & 3) * 8;
      gload16(A + (size_t)(m0 + row) * K + k0 + kc, (char*)As + c * 16);
      gload16(B + (size_t)(n0 + row) * K + k0 + kc, (char*)Bs + c * 16);
    }
    __syncthreads();
    short8 af[4], bfr[4];
#pragma unroll
    for (int rf = 0; rf < 4; ++rf)
      af[rf] = *(const short8*)(As + (wr + rf * 16 + (l & 15)) * 32 + (l >> 4) * 8);
#pragma unroll
    for (int cf = 0; cf < 4; ++cf)
      bfr[cf] = *(const short8*)(Bs + (wc + cf * 16 + (l & 15)) * 32 + (l >> 4) * 8);
#pragma unroll
    for (int rf = 0; rf < 4; ++rf)
#pragma unroll
      for (int cf = 0; cf < 4; ++cf)
        acc[rf][cf] = __builtin_amdgcn_mfma_f32_16x16x32_bf16(af[rf], bfr[cf], acc[rf][cf], 0, 0, 0);
    __syncthreads();
  }
#pragma unroll
  for (int cf = 0; cf < 4; ++cf) {
    int col = n0 + wc + cf * 16 + (l & 15);
#pragma unroll
    for (int rf = 0; rf < 4; ++rf) {
#pragma unroll
      for (int i = 0; i < 4; ++i) {
        int row = m0 + wr + rf * 16 + (l >> 4) * 4 + i;
        C[(size_t)row * N + col] = f2bf(acc[rf][cf][i]);
      }
    }
  }
}

// ---------- combined bias ----------
__global__ void k_bias(const float* __restrict__ Wxg, const float* __restrict__ bxg,
                       const float* __restrict__ b_in, const float* __restrict__ Whg,
                       const float* __restrict__ bhg, const float* __restrict__ b_hid,
                       float* __restrict__ gbias) {
  int col = blockIdx.x * 64 + (threadIdx.x >> 2);
  int p = threadIdx.x & 3;
  const float* wx = Wxg + (size_t)col * 1024;
  const float* wh = Whg + (size_t)col * 1024;
  float s = 0.f;
  for (int k = p * 256; k < p * 256 + 256; ++k)
    s += wx[k] * b_in[k] + wh[k] * b_hid[k];
  s += __shfl_down(s, 2, 4);
  s += __shfl_down(s, 1, 4);
  if (p == 0) gbias[col] = s + bxg[col] + bhg[col];
}

// ---------- fused: 64 scan blocks (R8 protocol) + 192 GX-GEMM workers ----------
// Workers pull 128x128 tiles (t-ascending) off a queue, compute GX tile
// (Xbf @ Wxc^T + gbias) in fp16, repack via LDS, store packed u64 sc0/sc1
// (straight to L3), then vmcnt(0)+barrier+atomicAdd(gxcnt[t-pair]).
// Scan blocks gate step t on gxcnt[t>>1]==32 via a monotone watermark
// (one L3 read per 2 steps, before the GX prefetch + h-poll).
__global__ __launch_bounds__(256, 1) void k_fused(
    const unsigned short* __restrict__ Xbf,  // bf16 [16384][1024]
    const unsigned short* __restrict__ Wxc,  // bf16 [4096][1024]
    const float* __restrict__ gbias,         // f32 [4096]
    unsigned short* __restrict__ GX2,        // fp16 tiled [256][64][4][64][16]
    const unsigned short* __restrict__ Whc,  // bf16 [4096][1024]
    const float* __restrict__ cell,          // [64][1024] f32
    unsigned short* __restrict__ hT,         // bf16 [4][64][64][16]
    float* __restrict__ out,                 // h [64][1024], c [64][1024] f32
    unsigned* __restrict__ flags,            // [4 groups][32 u32]: 16 tags/line
    unsigned* __restrict__ gxcnt,            // [128] tiles-done per t-pair
    unsigned* __restrict__ workctr) {        // work-queue counter
  __shared__ __align__(16) char smem[139264];
  const int tid = threadIdx.x;
  const int bid = blockIdx.x;

  if (bid >= SEQ_BLOCKS) {
    // ================= GEMM worker role =================
    unsigned short* As = (unsigned short*)smem;
    unsigned short* Bs = As + 128 * 32;
    unsigned short* T  = (unsigned short*)(smem + 16384);  // fp16 [128][136]
    unsigned* tbox = (unsigned*)(smem + 139256);
    const int wv = tid >> 6, l = tid & 63;
    const int wr = (wv >> 1) * 64, wc = (wv & 1) * 64;
    for (;;) {
      __syncthreads();
      if (tid == 0)
        *tbox = __hip_atomic_fetch_add(workctr, 1u, __ATOMIC_RELAXED, __HIP_MEMORY_SCOPE_AGENT);
      __syncthreads();
      unsigned tile = *tbox;
      if (tile >= GX_TILES) break;
      const int p = tile >> 5, xt = tile & 31;
      const int m0 = p * 128, n0 = xt * 128;
      f32x4 acc[4][4] = {};
      for (int k0 = 0; k0 < 1024; k0 += 32) {
#pragma unroll
        for (int j = 0; j < 2; ++j) {
          int c = wv * 128 + j * 64 + l;
          int row = c >> 2, kc = (c & 3) * 8;
          gload16(Xbf + (size_t)(m0 + row) * 1024 + k0 + kc, (char*)As + c * 16);
          gload16(Wxc + (size_t)(n0 + row) * 1024 + k0 + kc, (char*)Bs + c * 16);
        }
        __syncthreads();
        short8 af[4], bfr[4];
#pragma unroll
        for (int rf = 0; rf < 4; ++rf)
          af[rf] = *(const short8*)(As + (wr + rf * 16 + (l & 15)) * 32 + (l >> 4) * 8);
#pragma unroll
        for (int cf = 0; cf < 4; ++cf)
          bfr[cf] = *(const short8*)(Bs + (wc + cf * 16 + (l & 15)) * 32 + (l >> 4) * 8);
#pragma unroll
        for (int rf = 0; rf < 4; ++rf)
#pragma unroll
          for (int cf = 0; cf < 4; ++cf)
            acc[rf][cf] = __builtin_amdgcn_mfma_f32_16x16x32_bf16(af[rf], bfr[cf], acc[rf][cf], 0, 0, 0);
        __syncthreads();
      }
      // epilogue: +bias, fp16, stage tile in LDS
#pragma unroll
      for (int cf = 0; cf < 4; ++cf) {
        int cl = wc + cf * 16 + (l & 15);
        float bv = gbias[n0 + cl];
#pragma unroll
        for (int rf = 0; rf < 4; ++rf)
#pragma unroll
          for (int i = 0; i < 4; ++i)
            T[(wr + rf * 16 + (l >> 4) * 4 + i) * 136 + cl] = f2h(acc[rf][cf][i] + bv);
      }
      __syncthreads();
      // packed u64 sc0/sc1 stores: 16 spans of 2KB (one per (t2, blk))
      const int g = xt >> 3, blks0 = (xt & 7) * 8;
#pragma unroll
      for (int pp = 0; pp < 8; ++pp) {
        int s = pp * 2 + (tid >> 7);
        int t2 = s >> 3, blkL = s & 7;
        int k = tid & 127, b = k >> 1, half = k & 1;
        const unsigned long long* src =
            (const unsigned long long*)(T + (t2 * 64 + b) * 136 + blkL * 16 + half * 8);
        unsigned long long* dst = (unsigned long long*)(
            GX2 + ((size_t)((2 * p + t2) * 64 + blks0 + blkL)) * 4096 + g * 1024 + b * 16 + half * 8);
        __hip_atomic_store(dst, src[0], __ATOMIC_RELAXED, __HIP_MEMORY_SCOPE_AGENT);
        __hip_atomic_store(dst + 1, src[1], __ATOMIC_RELAXED, __HIP_MEMORY_SCOPE_AGENT);
      }
      asm volatile("s_waitcnt vmcnt(0)" ::: "memory");  // stores at L3
      __syncthreads();
      if (tid == 0)
        __hip_atomic_fetch_add(&gxcnt[p], 1u, __ATOMIC_RELAXED, __HIP_MEMORY_SCOPE_AGENT);
    }
    return;
  }

  // ================= scan role (R8 protocol + GX gating) =================
  float* pbuf = (float*)smem;  // (t&1)*17408 + s*4352 + gc*68 + b
  const int wv = tid >> 6, l = tid & 63;
  const int a = l & 15, q = l >> 4;

  short8 w[4][8];
#pragma unroll
  for (int ct = 0; ct < 4; ++ct)
#pragma unroll
    for (int u = 0; u < 8; ++u)
      w[ct][u] = *(const short8*)(
          Whc + (size_t)(ct * 1024 + bid * 16 + a) * 1024 + wv * 256 + u * 32 + q * 8);

  const int eb = tid >> 2;
  const int ej = (tid & 3) * 4;
  float c_reg[4];
  {
    float4 c4 = *(const float4*)(cell + (size_t)eb * 1024 + bid * 16 + ej);
    c_reg[0] = c4.x; c_reg[1] = c4.y; c_reg[2] = c4.z; c_reg[3] = c4.w;
  }

  const size_t abase = (size_t)(wv * 16 + (q >> 1)) * 1024 + a * 16 + (q & 1) * 8;
  const unsigned* pollp = flags + wv * 32 + a;
  int gxsafe = 0;

  for (int t = 0; t < 256; ++t) {
    // --- gate on GX tile availability (monotone watermark) ---
    const int pw = t >> 1;
    while (gxsafe <= pw) {
      unsigned v = __hip_atomic_load(&gxcnt[gxsafe], __ATOMIC_RELAXED, __HIP_MEMORY_SCOPE_AGENT);
      if (v >= 32u) ++gxsafe;
      else __builtin_amdgcn_s_sleep(2);
    }
    __builtin_amdgcn_fence(__ATOMIC_ACQUIRE, "workgroup");

    // --- GX prefetch (plain cached loads; worker wrote via L3) ---
    const unsigned short* chunk = GX2 + ((size_t)t * 64 + bid) * 4096;
    unsigned long long gxu[4];
#pragma unroll
    for (int g = 0; g < 4; ++g)
      gxu[g] = *(const unsigned long long*)(chunk + (g * 64 + eb) * 16 + ej);

    // --- wait for the 16 source-block tags (ONE line per wave) ---
    if (t > 0) {
      const unsigned tgt = (unsigned)t;
      for (;;) {
        unsigned v = __hip_atomic_load(pollp, __ATOMIC_RELAXED, __HIP_MEMORY_SCOPE_AGENT);
        if (__all((int)(v >= tgt))) break;
        __builtin_amdgcn_s_sleep(1);
      }
      __builtin_amdgcn_fence(__ATOMIC_ACQUIRE, "workgroup");
      __builtin_amdgcn_sched_barrier(0);
    }

    // --- load A from compact hT messages (L3-only sc0/sc1) ---
    const unsigned short* hb = hT + ((size_t)(t & 3) << 16) + abase;
    short8 afr[4][8];
#pragma unroll
    for (int u = 0; u < 8; ++u)
#pragma unroll
      for (int rt = 0; rt < 4; ++rt)
        afr[rt][u] = load_h16(hb + u * 2048 + rt * 256);

    // --- 128 MFMA, all operands in registers ---
    f32x4 acc[4][4] = {};
#pragma unroll
    for (int u = 0; u < 8; ++u)
#pragma unroll
      for (int rt = 0; rt < 4; ++rt)
#pragma unroll
        for (int ct = 0; ct < 4; ++ct)
          acc[rt][ct] = __builtin_amdgcn_mfma_f32_16x16x32_bf16(afr[rt][u], w[ct][u],
                                                                acc[rt][ct], 0, 0, 0);

    // --- partials to LDS (0-conflict layout): f32x4 over batch ---
    const int pb = (t & 1) * 17408 + wv * 4352;
#pragma unroll
    for (int rt = 0; rt < 4; ++rt)
#pragma unroll
      for (int ct = 0; ct < 4; ++ct) {
        int gc = a * 4 + ct;
        int b0 = (rt * 16 + q * 4) ^ ((((gc) >> 3) & 3) << 2);
        *(f32x4*)&pbuf[pb + gc * 68 + b0] = acc[rt][ct];
      }
    __syncthreads();

    // --- reduce 4 k-slots + GX, gates for (row eb, cols ej..ej+3) ---
    const int pr = (t & 1) * 17408;
    float sg[4][4];
#pragma unroll
    for (int g = 0; g < 4; ++g) {
      unsigned short gx4[4];
      __builtin_memcpy(gx4, &gxu[g], 8);
#pragma unroll
      for (int i = 0; i < 4; ++i) {
        int gc = (ej + i) * 4 + g;
        int bx = eb ^ ((((gc) >> 3) & 3) << 2);
        float s = pbuf[pr + 0 * 4352 + gc * 68 + bx] + pbuf[pr + 1 * 4352 + gc * 68 + bx] +
                  pbuf[pr + 2 * 4352 + gc * 68 + bx] + pbuf[pr + 3 * 4352 + gc * 68 + bx];
        sg[g][i] = s + h2f(gx4[i]);
      }
    }
    float hnew[4];
#pragma unroll
    for (int i = 0; i < 4; ++i) {
      float ig = fast_sigmoid(sg[0][i]);
      float fg = fast_sigmoid(sg[1][i]);
      float gg = fast_tanh(sg[2][i]);
      float og = fast_sigmoid(sg[3][i]);
      c_reg[i] = fg * c_reg[i] + ig * gg;
      hnew[i] = og * fast_tanh(c_reg[i]);
    }

    if (t == 255) {
      float4 h4 = {hnew[0], hnew[1], hnew[2], hnew[3]};
      float4 c4 = {c_reg[0], c_reg[1], c_reg[2], c_reg[3]};
      *(float4*)(out + (size_t)eb * 1024 + bid * 16 + ej) = h4;
      *(float4*)(out + 65536 + (size_t)eb * 1024 + bid * 16 + ej) = c4;
    } else {
      unsigned short hs[4] = {f2bf(hnew[0]), f2bf(hnew[1]), f2bf(hnew[2]), f2bf(hnew[3])};
      unsigned long long hv;
      __builtin_memcpy(&hv, hs, 8);
      __hip_atomic_store(
          (unsigned long long*)(hT + ((size_t)((t + 1) & 3) << 16) + (size_t)bid * 1024 +
                                eb * 16 + ej),
          hv, __ATOMIC_RELAXED, __HIP_MEMORY_SCOPE_AGENT);
      asm volatile("s_waitcnt vmcnt(0)" ::: "memory");
      __syncthreads();
      if (tid == 0)
        __hip_atomic_store(&flags[(bid >> 4) * 32 + (bid & 15)], (unsigned)(t + 1),
                           __ATOMIC_RELAXED, __HIP_MEMORY_SCOPE_AGENT);
    }
  }
}

extern "C" void kernel_launch(void* const* d_in, const int* in_sizes, int n_in,
                              void* d_out, int out_size, void* d_ws, size_t ws_size,
                              hipStream_t stream) {
  const float* x      = (const float*)d_in[0];
  const float* hidden = (const float*)d_in[1];
  const float* cell   = (const float*)d_in[2];
  const float* W_in   = (const float*)d_in[3];
  const float* b_in   = (const float*)d_in[4];
  const float* W_hid  = (const float*)d_in[5];
  const float* b_hid  = (const float*)d_in[6];
  const float* Wx_g   = (const float*)d_in[7];
  const float* bx_g   = (const float*)d_in[8];
  const float* Wh_g   = (const float*)d_in[9];
  const float* bh_g   = (const float*)d_in[10];
  float* out = (float*)d_out;

  char* ws = (char*)d_ws;
  unsigned short* GX2   = (unsigned short*)(ws);                 // 134217728 (written by workers)
  unsigned short* Xbf   = (unsigned short*)(ws + 134217728);     // 33554432 (LIVE through fused)
  unsigned short* WxGb  = (unsigned short*)(ws + 167772160);     // 8388608 (dead after combine 1)
  unsigned short* WhGb  = (unsigned short*)(ws + 176160768);     // 8388608
  unsigned short* WinT  = (unsigned short*)(ws + 184549376);     // 2097152 (dead after combines)
  unsigned short* WhidT = (unsigned short*)(ws + 186646528);     // 2097152
  unsigned short* Wxc   = (unsigned short*)(ws + 188743680);     // 8388608 (LIVE through fused)
  unsigned short* Whc   = (unsigned short*)(ws + 197132288);     // 8388608
  float*          gbias = (float*)(ws + 205520896);              // 16384
  unsigned short* hT    = (unsigned short*)(ws + 167772160);     // 1 MB (overlays WxGb)
  unsigned*       ctrl  = (unsigned*)(ws + 184549376);           // 4 KB (overlays WinT)
  unsigned*       flags = ctrl;                                  // 512 B
  unsigned*       gxcnt = ctrl + 256;                            // 512 B (128 u32)
  unsigned*       wctr  = ctrl + 512;                            // 4 B

  // converts
  k_conv_bf16<<<16384, 256, 0, stream>>>(x, Xbf);
  k_conv_bf16<<<4096, 256, 0, stream>>>(Wx_g, WxGb);
  k_conv_bf16<<<4096, 256, 0, stream>>>(Wh_g, WhGb);
  k_transpose<<<dim3(32, 32), 256, 0, stream>>>(W_in, WinT, 1024, 1024);
  k_transpose<<<dim3(32, 32), 256, 0, stream>>>(W_hid, WhidT, 1024, 1024);
  // combined weights: Wxc = WxG @ W_in (via W_in^T), Whc = WhG @ W_hid
  k_gemm_bt<<<dim3(8, 32), 256, 0, stream>>>(WxGb, WinT, Wxc, 4096, 1024, 1024);
  k_gemm_bt<<<dim3(8, 32), 256, 0, stream>>>(WhGb, WhidT, Whc, 4096, 1024, 1024);
  k_bias<<<64, 256, 0, stream>>>(Wx_g, bx_g, b_in, Wh_g, bh_g, b_hid, gbias);
  // h0 into hT slot 0 (overlays WxGb — dead after combine GEMM 1)
  k_h0t<<<64, 256, 0, stream>>>(hidden, hT);
  // control region: tags + gx counters + work counter
  hipMemsetAsync(ctrl, 0, 4096, stream);
  // fused scan + GX-GEMM workers
  k_fused<<<256, 256, 0, stream>>>(Xbf, Wxc, gbias, GX2, Whc, cell, hT, out,
                                   flags, gxcnt, wctr);
}